// Round 13
// baseline (187.903 us; speedup 1.0000x reference)
//
#include <hip/hip_runtime.h>
#include <cstdint>

typedef __bf16 bf16x8 __attribute__((ext_vector_type(8)));
typedef float  f32x4  __attribute__((ext_vector_type(4)));

#define LOG2E 1.4426950408889634f
#define LGKM0 do { asm volatile("s_waitcnt lgkmcnt(0)" ::: "memory"); \
                   __builtin_amdgcn_sched_barrier(0); } while (0)

// split 8 f32 into hi/lo bf16 fragments (hi+lo ~ 16-bit mantissa)
__device__ __forceinline__ void split8(const float* v, bf16x8& hi, bf16x8& lo) {
    union { bf16x8 v; __bf16 e[8]; } h, l;
    #pragma unroll
    for (int j = 0; j < 8; j++) {
        __bf16 hb = (__bf16)v[j];
        float  r  = v[j] - (float)hb;
        h.e[j] = hb; l.e[j] = (__bf16)r;
    }
    hi = h.v; lo = l.v;
}
__device__ __forceinline__ bf16x8 cvt8(const float* v) {
    union { bf16x8 v; __bf16 e[8]; } u;
    #pragma unroll
    for (int j = 0; j < 8; j++) u.e[j] = (__bf16)v[j];
    return u.v;
}
__device__ __forceinline__ void splitstore(unsigned short* ph, unsigned short* pl, float v) {
    __bf16 hb = (__bf16)v;
    float  r  = v - (float)hb;
    __bf16 lb = (__bf16)r;
    unsigned short hu, lu;
    __builtin_memcpy(&hu, &hb, 2); __builtin_memcpy(&lu, &lb, 2);
    *ph = hu; *pl = lu;
}
__device__ __forceinline__ unsigned short f2bfh(float v) {
    __bf16 hb = (__bf16)v; unsigned short hu;
    __builtin_memcpy(&hu, &hb, 2); return hu;
}

// ---------------- Kpre2: k1-GEMM (0..255) + acc-zero (256..1363) + bitpack ----
__global__ __launch_bounds__(256)
void kpre2(const int* __restrict__ adj, unsigned long long* __restrict__ bm64,
           const float* __restrict__ x, const float* __restrict__ w1,
           const float* __restrict__ a11, const float* __restrict__ a21,
           unsigned short* __restrict__ h1t_hi, float* __restrict__ fvals,
           float4* __restrict__ pzero) {
    int bx = blockIdx.x, tid = threadIdx.x;
    if (bx < 256) {
        // ---- k1 role: H1T[c][i] = (x @ W1^T)[i][c] bf16-hi + f1/f2 epilogue
        int wave = tid >> 6, lane = tid & 63;
        int q = lane >> 4, m = lane & 15;
        int i0 = bx * 16;
        int c0 = wave * 64;                     // wave == head
        f32x4 acc[4] = {};
        #pragma unroll
        for (int k0 = 0; k0 < 256; k0 += 32) {
            bf16x8 ah, al;
            split8(x + (i0 + m) * 256 + k0 + q * 8, ah, al);
            #pragma unroll
            for (int ct = 0; ct < 4; ct++) {
                bf16x8 bh, bl;
                split8(w1 + (c0 + ct * 16 + m) * 256 + k0 + q * 8, bh, bl);
                acc[ct] = __builtin_amdgcn_mfma_f32_16x16x32_bf16(ah, bh, acc[ct], 0, 0, 0);
                acc[ct] = __builtin_amdgcn_mfma_f32_16x16x32_bf16(al, bh, acc[ct], 0, 0, 0);
                acc[ct] = __builtin_amdgcn_mfma_f32_16x16x32_bf16(ah, bl, acc[ct], 0, 0, 0);
            }
        }
        float a1v[4], a2v[4];
        #pragma unroll
        for (int ct = 0; ct < 4; ct++) {
            a1v[ct] = a11[wave * 64 + ct * 16 + m];
            a2v[ct] = a21[wave * 64 + ct * 16 + m];
        }
        #pragma unroll
        for (int r = 0; r < 4; r++) {
            int i = i0 + q * 4 + r;
            float s1 = 0.f, s2 = 0.f;
            #pragma unroll
            for (int ct = 0; ct < 4; ct++) {
                int c = c0 + ct * 16 + m;
                h1t_hi[c * 4096 + i] = f2bfh(acc[ct][r]);
                s1 += acc[ct][r] * a1v[ct];
                s2 += acc[ct][r] * a2v[ct];
            }
            #pragma unroll
            for (int off = 1; off < 16; off <<= 1) {
                s1 += __shfl_xor(s1, off);
                s2 += __shfl_xor(s2, off);
            }
            if (m == 0) {
                fvals[wave * 4096 + i] = s1 * LOG2E;
                fvals[16384 + wave * 4096 + i] = s2 * LOG2E;
            }
        }
        return;
    }
    if (bx < 1364) {
        // ---- accumulator-zero role (1108 blocks x 256 thr x 16B = 4.54MB)
        pzero[(size_t)(bx - 256) * 256 + tid] = float4{0.f, 0.f, 0.f, 0.f};
        return;
    }
    // ---- adj bitpack role (8192 blocks)
    int bxa = bx - 1364;
    int row = bxa >> 1, jbase = (bxa & 1) * 2048;
    int wave = tid >> 6, lane = tid & 63;
    const int* base = adj + (size_t)row * 4096 + jbase + wave * 512;
    unsigned long long* bmw = bm64 + row * 64 + (jbase >> 6) + wave * 8;
    #pragma unroll
    for (int it = 0; it < 8; it++) {
        int v = base[it * 64 + lane];
        unsigned long long mask = __ballot(v != 0);
        if (lane == 0) bmw[it] = mask;
    }
}

// ---------------- attention (64-row tiles, 1 group/wave, RAW barriers) --------
// R12 lesson: the loop is LATENCY-bound, not LDS-BW-bound — 2-row-groups/wave
// (fewer waves, bigger LDS) collapsed occupancy to 20% and ran 3x slower.
// This is the R11 structure (measured-best) with JLEN shrunk to raise
// blocks/CU: attn1 JLEN=512 -> 2048 blocks, 29.7KB LDS -> 5 blocks/CU.
// FACTORED EXP (R11), raw s_barrier + lgkmcnt(0) (R6), z via MFMA (R9),
// atomic single-buffer accumulation (R10).
template<int NCT, int JLEN>
__global__ __launch_bounds__(256)
void attn_kernel(const unsigned char* __restrict__ bmb,
                 const float* __restrict__ f1_all,
                 const float* __restrict__ f2_all,
                 const unsigned short* __restrict__ BTh_all,
                 float* __restrict__ pacc,
                 float* __restrict__ zacc,
                 int pstride) {
    constexpr int S    = JLEN / 32;                 // mask u32 per row
    constexpr int ST   = (S % 8 == 0) ? S + 4 : S;  // bank-safe padded stride (even)
    constexpr int PR   = S / 4;                     // mask uint4 per row
    constexpr int R    = 64;                        // i-rows per block
    constexpr int NU4  = R * PR;
    constexpr int CR   = NCT * 16;                  // BT tile rows
    constexpr int TSTR = 72;                        // 64-j tile row stride (hw)
    constexpr int NIT  = JLEN / 64;                 // 64-j iterations (even, >=2)
    constexpr int BUFO = CR * TSTR;
    int tid = threadIdx.x, wave = tid >> 6, lane = tid & 63;
    int q = lane >> 4, m = lane & 15;
    int head = blockIdx.y;
    int i0 = blockIdx.x * R;
    int jstart = blockIdx.z * JLEN;

    __shared__ unsigned int ldsbm[R * ST];
    __shared__ unsigned short ldsbt[2][BUFO];
    __shared__ float ldsf2[JLEN];
    __shared__ float ldse2p[JLEN];
    __shared__ float ldse2n[JLEN];

    const unsigned short* BTh = BTh_all + (size_t)head * CR * 4096;
    const float* f1 = f1_all + head * 4096;
    const float* f2 = f2_all + head * 4096;

    // stage bitmask slice
    for (int c = tid; c < NU4; c += 256) {
        int row = c / PR, part = c % PR;
        uint4 v = *(const uint4*)(bmb + (size_t)(i0 + row) * 512 + (jstart >> 3) + part * 16);
        *(uint4*)&ldsbm[row * ST + part * 4] = v;
    }
    // stage f2 slice + factored-exp tables (f2 already log2e-scaled)
    for (int c = tid; c < JLEN / 4; c += 256) {
        float4 v = *(const float4*)(f2 + jstart + c * 4);
        *(float4*)&ldsf2[c * 4] = v;
        float4 ep, en;
        ep.x = __builtin_amdgcn_exp2f(v.x); en.x = __builtin_amdgcn_exp2f(0.01f * v.x);
        ep.y = __builtin_amdgcn_exp2f(v.y); en.y = __builtin_amdgcn_exp2f(0.01f * v.y);
        ep.z = __builtin_amdgcn_exp2f(v.z); en.z = __builtin_amdgcn_exp2f(0.01f * v.z);
        ep.w = __builtin_amdgcn_exp2f(v.w); en.w = __builtin_amdgcn_exp2f(0.01f * v.w);
        *(float4*)&ldse2p[c * 4] = ep;
        *(float4*)&ldse2n[c * 4] = en;
    }

    // BT staging: thread t stages row t>>2, cols (t&3)*8 + {0,32} of each tile
    int sc = tid >> 2, sp = tid & 3;
    bool stager = (NCT == 4) ? true : (tid < CR * 4);
    const unsigned short* sbase = BTh + (size_t)sc * 4096 + jstart + sp * 8;
    unsigned short* swr0 = &ldsbt[0][0] + sc * TSTR + sp * 8;

    uint4 vA0, vA1, vB0, vB1;
    if (stager) {
        uint4 t00 = *(const uint4*)(sbase);
        uint4 t01 = *(const uint4*)(sbase + 32);
        *(uint4*)(swr0) = t00;                      // tile 0 -> buf 0
        *(uint4*)(swr0 + 32) = t01;
        vB0 = *(const uint4*)(sbase + 64);          // tile 1 held in vB
        vB1 = *(const uint4*)(sbase + 96);
    }

    int col0 = head * CR;
    int r0 = wave * 16;
    float f1s0 = f1[i0 + r0 + m];
    float e1p0 = __builtin_amdgcn_exp2f(f1s0);
    float e1n0 = __builtin_amdgcn_exp2f(0.01f * f1s0);

    f32x4 acc0[NCT] = {};
    f32x4 accz = {};                                // z via MFMA (P @ ones)
    bf16x8 ones;
    {
        union { bf16x8 v; __bf16 e[8]; } o;
        #pragma unroll
        for (int j = 0; j < 8; j++) o.e[j] = (__bf16)1.0f;
        ones = o.v;
    }
    int mrow = (r0 + m) * ST;

    auto compute = [&](int it, int cur) {
        int jl = it * 64;
        unsigned long long mw = *(const unsigned long long*)&ldsbm[mrow + 2 * it];
        const unsigned short* rb = &ldsbt[0][0] + cur * BUFO;
        #pragma unroll
        for (int js = 0; js < 2; js++) {
            unsigned int md0 = (js == 0) ? (unsigned int)mw : (unsigned int)(mw >> 32);
            int jb = jl + js * 32 + q * 8;
            const float4* f2p = (const float4*)&ldsf2[jb];
            float4 fa = f2p[0], fb = f2p[1];
            const float4* epp = (const float4*)&ldse2p[jb];
            float4 pa = epp[0], pb = epp[1];
            const float4* enp = (const float4*)&ldse2n[jb];
            float4 na = enp[0], nb = enp[1];
            float fv[8] = {fa.x, fa.y, fa.z, fa.w, fb.x, fb.y, fb.z, fb.w};
            float ev[8] = {pa.x, pa.y, pa.z, pa.w, pb.x, pb.y, pb.z, pb.w};
            float nv[8] = {na.x, na.y, na.z, na.w, nb.x, nb.y, nb.z, nb.w};
            float pv0[8];
            #pragma unroll
            for (int jj = 0; jj < 8; jj++) {
                int bit = q * 8 + jj;
                float s0 = f1s0 + fv[jj];
                bool pos = s0 > 0.0f;
                float p0 = (pos ? e1p0 : e1n0) * (pos ? ev[jj] : nv[jj]);
                bool v0 = ((md0 >> bit) & 1u) && (s0 != 0.0f);
                pv0[jj] = v0 ? p0 : 0.0f;
            }
            bf16x8 ah0 = cvt8(pv0);
            #pragma unroll
            for (int ct = 0; ct < NCT; ct++) {
                bf16x8 bh = *(const bf16x8*)(rb + (ct * 16 + m) * TSTR + js * 32 + q * 8);
                acc0[ct] = __builtin_amdgcn_mfma_f32_16x16x32_bf16(ah0, bh, acc0[ct], 0, 0, 0);
            }
            accz = __builtin_amdgcn_mfma_f32_16x16x32_bf16(ah0, ones, accz, 0, 0, 0);
        }
    };

    LGKM0;                                           // publish prologue ds_writes
    for (int itp = 0; itp + 2 < NIT; itp += 2) {
        __builtin_amdgcn_s_barrier();
        if (stager) {                                // prefetch tile itp+2 -> vA
            vA0 = *(const uint4*)(sbase + (itp + 2) * 64);
            vA1 = *(const uint4*)(sbase + (itp + 2) * 64 + 32);
        }
        compute(itp, 0);
        if (stager) {                                // write tile itp+1 -> buf1
            *(uint4*)(swr0 + BUFO) = vB0;
            *(uint4*)(swr0 + BUFO + 32) = vB1;
        }
        LGKM0;
        __builtin_amdgcn_s_barrier();
        if (stager) {                                // prefetch tile itp+3 -> vB
            vB0 = *(const uint4*)(sbase + (itp + 3) * 64);
            vB1 = *(const uint4*)(sbase + (itp + 3) * 64 + 32);
        }
        compute(itp + 1, 1);
        if (stager) {                                // write tile itp+2 -> buf0
            *(uint4*)(swr0) = vA0;
            *(uint4*)(swr0 + 32) = vA1;
        }
        LGKM0;
    }
    __builtin_amdgcn_s_barrier();
    compute(NIT - 2, 0);
    if (stager) {                                    // write tile NIT-1 -> buf1
        *(uint4*)(swr0 + BUFO) = vB0;
        *(uint4*)(swr0 + BUFO + 32) = vB1;
    }
    LGKM0;
    __builtin_amdgcn_s_barrier();
    compute(NIT - 1, 1);

    // z epilogue: accz reg r holds z[i0+r0+q*4+r] (replicated over m)
    if (m == 0) {
        #pragma unroll
        for (int r = 0; r < 4; r++) {
            int zi = head * 4096 + i0 + r0 + q * 4 + r;
            atomicAdd(&zacc[zi], accz[r]);
        }
    }
    #pragma unroll
    for (int ct = 0; ct < NCT; ct++)
        #pragma unroll
        for (int r = 0; r < 4; r++) {
            int col = col0 + ct * 16 + m;
            int rowA = i0 + r0 + q * 4 + r;
            atomicAdd(&pacc[rowA * pstride + col], acc0[ct][r]);
        }
}

// ---------------- Fin1c: helu = elu(p1 / z1), coalesced, hi/lo bf16 -----------
__global__ __launch_bounds__(256)
void fin1c(const float* __restrict__ pp, const float* __restrict__ zp,
           unsigned short* __restrict__ hh, unsigned short* __restrict__ hl) {
    int row = blockIdx.x, col = threadIdx.x;
    float s = pp[(size_t)row * 256 + col];
    int head = col >> 6;
    float zz = zp[head * 4096 + row];
    float v = s / zz;
    v = (v > 0.f) ? v : (__expf(v) - 1.0f);
    splitstore(&hh[row * 256 + col], &hl[row * 256 + col], v);
}

// ---------------- K3: h2 = h_elu @ W2^T (in-register W2 split), fq ------------
__global__ __launch_bounds__(256)
void k3_layer2(const unsigned short* __restrict__ helu_hi,
               const unsigned short* __restrict__ helu_lo,
               const float* __restrict__ w2,
               const float* __restrict__ a12,
               const float* __restrict__ a22,
               unsigned short* __restrict__ h2t_hi,
               float* __restrict__ fq) {
    int tid = threadIdx.x, wave = tid >> 6, lane = tid & 63;
    int q = lane >> 4, m = lane & 15;
    int i0 = (blockIdx.x * 4 + wave) * 16;
    f32x4 acc = {};
    #pragma unroll
    for (int k0 = 0; k0 < 256; k0 += 32) {
        bf16x8 ah = *(const bf16x8*)(helu_hi + (i0 + m) * 256 + k0 + q * 8);
        bf16x8 al = *(const bf16x8*)(helu_lo + (i0 + m) * 256 + k0 + q * 8);
        bf16x8 bh, bl;
        split8(w2 + m * 256 + k0 + q * 8, bh, bl);
        acc = __builtin_amdgcn_mfma_f32_16x16x32_bf16(ah, bh, acc, 0, 0, 0);
        acc = __builtin_amdgcn_mfma_f32_16x16x32_bf16(al, bh, acc, 0, 0, 0);
        acc = __builtin_amdgcn_mfma_f32_16x16x32_bf16(ah, bl, acc, 0, 0, 0);
    }
    float a1v = a12[m], a2v = a22[m];
    #pragma unroll
    for (int r = 0; r < 4; r++) {
        float v = acc[r];
        int i = i0 + q * 4 + r;
        h2t_hi[m * 4096 + i] = f2bfh(v);
        float s1 = v * a1v, s2 = v * a2v;
        #pragma unroll
        for (int off = 1; off < 16; off <<= 1) {
            s1 += __shfl_xor(s1, off);
            s2 += __shfl_xor(s2, off);
        }
        if (m == 0) { fq[i] = s1 * LOG2E; fq[4096 + i] = s2 * LOG2E; }
    }
}

// ---------------- Fin2: out = p2/z2 (f32, single atomic-accumulated buffers) --
__global__ __launch_bounds__(128)
void fin2(const float* __restrict__ pp, const float* __restrict__ zp,
          float* __restrict__ out) {
    int idx = blockIdx.x * 128 + threadIdx.x;      // 65536
    out[idx] = pp[idx] / zp[idx >> 4];
}

extern "C" void kernel_launch(void* const* d_in, const int* in_sizes, int n_in,
                              void* d_out, int out_size, void* d_ws, size_t ws_size,
                              hipStream_t stream) {
    const float* x   = (const float*)d_in[0];
    const int*   adj = (const int*)d_in[1];
    const float* w1  = (const float*)d_in[2];
    const float* a11 = (const float*)d_in[3];
    const float* a21 = (const float*)d_in[4];
    const float* w2  = (const float*)d_in[5];
    const float* a12 = (const float*)d_in[6];
    const float* a22 = (const float*)d_in[7];
    float* out = (float*)d_out;

    uint8_t* w = (uint8_t*)d_ws;
    unsigned long long* bm  = (unsigned long long*)(w);                       // 2 MB
    unsigned short* h1t_hi  = (unsigned short*)(w + (2u << 20));              // 2 MB
    unsigned short* h2t_hi  = (unsigned short*)(w + (4u << 20));              // 128 KB
    float*          fvals   = (float*)(w + (4u << 20) + (128u << 10));        // 128 KB
    float*          fq      = (float*)(w + (4u << 20) + (256u << 10));        // 32 KB
    unsigned short* helu_hi = (unsigned short*)(w + (4u << 20) + (560u << 10)); // 2 MB
    unsigned short* helu_lo = (unsigned short*)(w + (4u << 20) + (2608u << 10)); // 2 MB

    // atomic accumulators (contiguous, zeroed by kpre2's zero role):
    // p1 4MB | z1 64KB | p2 256KB | z2 16KB  = 4.33 MB
    float* p1 = (float*)(w + (9u << 20));
    float* z1 = p1 + (size_t)4096 * 256;
    float* p2 = z1 + 4 * 4096;
    float* z2 = p2 + 4096 * 16;

    kpre2<<<9556, 256, 0, stream>>>(adj, bm, x, w1, a11, a21, h1t_hi, fvals,
                                    (float4*)p1);
    attn_kernel<4, 512><<<dim3(64, 4, 8), 256, 0, stream>>>(
        (const unsigned char*)bm, fvals, fvals + 16384, h1t_hi, p1, z1, 256);
    fin1c<<<4096, 256, 0, stream>>>(p1, z1, helu_hi, helu_lo);
    k3_layer2<<<64, 256, 0, stream>>>(helu_hi, helu_lo, w2, a12, a22,
                                      h2t_hi, fq);
    attn_kernel<1, 128><<<dim3(64, 1, 32), 256, 0, stream>>>(
        (const unsigned char*)bm, fq, fq + 4096, h2t_hi, p2, z2, 16);
    fin2<<<512, 128, 0, stream>>>(p2, z2, out);
}

// Round 14
// 170.925 us; speedup vs baseline: 1.0993x; 1.0993x over previous
//
#include <hip/hip_runtime.h>
#include <cstdint>

typedef __bf16 bf16x8 __attribute__((ext_vector_type(8)));
typedef float  f32x4  __attribute__((ext_vector_type(4)));

#define LOG2E 1.4426950408889634f
#define LGKM0 do { asm volatile("s_waitcnt lgkmcnt(0)" ::: "memory"); \
                   __builtin_amdgcn_sched_barrier(0); } while (0)

// split 8 f32 into hi/lo bf16 fragments (hi+lo ~ 16-bit mantissa)
__device__ __forceinline__ void split8(const float* v, bf16x8& hi, bf16x8& lo) {
    union { bf16x8 v; __bf16 e[8]; } h, l;
    #pragma unroll
    for (int j = 0; j < 8; j++) {
        __bf16 hb = (__bf16)v[j];
        float  r  = v[j] - (float)hb;
        h.e[j] = hb; l.e[j] = (__bf16)r;
    }
    hi = h.v; lo = l.v;
}
__device__ __forceinline__ bf16x8 cvt8(const float* v) {
    union { bf16x8 v; __bf16 e[8]; } u;
    #pragma unroll
    for (int j = 0; j < 8; j++) u.e[j] = (__bf16)v[j];
    return u.v;
}
__device__ __forceinline__ void splitstore(unsigned short* ph, unsigned short* pl, float v) {
    __bf16 hb = (__bf16)v;
    float  r  = v - (float)hb;
    __bf16 lb = (__bf16)r;
    unsigned short hu, lu;
    __builtin_memcpy(&hu, &hb, 2); __builtin_memcpy(&lu, &lb, 2);
    *ph = hu; *pl = lu;
}
__device__ __forceinline__ unsigned short f2bfh(float v) {
    __bf16 hb = (__bf16)v; unsigned short hu;
    __builtin_memcpy(&hu, &hb, 2); return hu;
}

// ---------------- Kpre2: k1-GEMM (0..255) + acc-zero (256..1363) + bitpack ----
__global__ __launch_bounds__(256)
void kpre2(const int* __restrict__ adj, unsigned long long* __restrict__ bm64,
           const float* __restrict__ x, const float* __restrict__ w1,
           const float* __restrict__ a11, const float* __restrict__ a21,
           unsigned short* __restrict__ h1t_hi, float* __restrict__ fvals,
           float4* __restrict__ pzero) {
    int bx = blockIdx.x, tid = threadIdx.x;
    if (bx < 256) {
        // ---- k1 role: H1T[c][i] = (x @ W1^T)[i][c] bf16-hi + f1/f2 epilogue
        int wave = tid >> 6, lane = tid & 63;
        int q = lane >> 4, m = lane & 15;
        int i0 = bx * 16;
        int c0 = wave * 64;                     // wave == head
        f32x4 acc[4] = {};
        #pragma unroll
        for (int k0 = 0; k0 < 256; k0 += 32) {
            bf16x8 ah, al;
            split8(x + (i0 + m) * 256 + k0 + q * 8, ah, al);
            #pragma unroll
            for (int ct = 0; ct < 4; ct++) {
                bf16x8 bh, bl;
                split8(w1 + (c0 + ct * 16 + m) * 256 + k0 + q * 8, bh, bl);
                acc[ct] = __builtin_amdgcn_mfma_f32_16x16x32_bf16(ah, bh, acc[ct], 0, 0, 0);
                acc[ct] = __builtin_amdgcn_mfma_f32_16x16x32_bf16(al, bh, acc[ct], 0, 0, 0);
                acc[ct] = __builtin_amdgcn_mfma_f32_16x16x32_bf16(ah, bl, acc[ct], 0, 0, 0);
            }
        }
        float a1v[4], a2v[4];
        #pragma unroll
        for (int ct = 0; ct < 4; ct++) {
            a1v[ct] = a11[wave * 64 + ct * 16 + m];
            a2v[ct] = a21[wave * 64 + ct * 16 + m];
        }
        #pragma unroll
        for (int r = 0; r < 4; r++) {
            int i = i0 + q * 4 + r;
            float s1 = 0.f, s2 = 0.f;
            #pragma unroll
            for (int ct = 0; ct < 4; ct++) {
                int c = c0 + ct * 16 + m;
                h1t_hi[c * 4096 + i] = f2bfh(acc[ct][r]);
                s1 += acc[ct][r] * a1v[ct];
                s2 += acc[ct][r] * a2v[ct];
            }
            #pragma unroll
            for (int off = 1; off < 16; off <<= 1) {
                s1 += __shfl_xor(s1, off);
                s2 += __shfl_xor(s2, off);
            }
            if (m == 0) {
                fvals[wave * 4096 + i] = s1 * LOG2E;
                fvals[16384 + wave * 4096 + i] = s2 * LOG2E;
            }
        }
        return;
    }
    if (bx < 1364) {
        // ---- accumulator-zero role (1108 blocks x 256 thr x 16B = 4.54MB)
        pzero[(size_t)(bx - 256) * 256 + tid] = float4{0.f, 0.f, 0.f, 0.f};
        return;
    }
    // ---- adj bitpack role (8192 blocks)
    int bxa = bx - 1364;
    int row = bxa >> 1, jbase = (bxa & 1) * 2048;
    int wave = tid >> 6, lane = tid & 63;
    const int* base = adj + (size_t)row * 4096 + jbase + wave * 512;
    unsigned long long* bmw = bm64 + row * 64 + (jbase >> 6) + wave * 8;
    #pragma unroll
    for (int it = 0; it < 8; it++) {
        int v = base[it * 64 + lane];
        unsigned long long mask = __ballot(v != 0);
        if (lane == 0) bmw[it] = mask;
    }
}

// ---------------- attention (64-row tiles, 64-j iters, RAW barriers, atomic) --
// no-max-subtraction softmax (e bounded). fvals pre-scaled by log2e.
// FACTORED EXP: p = pos ? 2^f1'*2^f2' : 2^(.01f1')*2^(.01f2') (R11).
// BT staged through LDS (direct per-lane reads = 16-line gathers, R4 = 67us).
// Raw s_barrier + lgkmcnt(0) only (R6). z via MFMA (P @ ones, R9). Atomic
// accumulation into single coherence-point p/z buffers (R10).
// CONFIG NOTE (R12/R13 bracket): JLEN=1024/z=4 is the measured optimum —
// bigger tiles (R12: 2 row-groups/wave, 48KB LDS) collapse occupancy to 20%
// (latency-bound, 61us); more chunks (R13: JLEN=512/z=8) double the atomic
// p-write traffic which is coherence-level, ~1TB/s (45us, WRITE_SIZE 35MB).
template<int NCT, int JLEN>
__global__ __launch_bounds__(256)
void attn_kernel(const unsigned char* __restrict__ bmb,
                 const float* __restrict__ f1_all,
                 const float* __restrict__ f2_all,
                 const unsigned short* __restrict__ BTh_all,
                 float* __restrict__ pacc,
                 float* __restrict__ zacc,
                 int pstride) {
    constexpr int S    = JLEN / 32;                 // mask u32 per row
    constexpr int ST   = (S % 8 == 0) ? S + 4 : S;  // bank-safe padded stride (even)
    constexpr int PR   = S / 4;                     // mask uint4 per row
    constexpr int R    = 64;                        // i-rows per block
    constexpr int NU4  = R * PR;
    constexpr int CR   = NCT * 16;                  // BT tile rows
    constexpr int TSTR = 72;                        // 64-j tile row stride (hw)
    constexpr int NIT  = JLEN / 64;                 // 64-j iterations (even, >=4)
    constexpr int BUFO = CR * TSTR;
    int tid = threadIdx.x, wave = tid >> 6, lane = tid & 63;
    int q = lane >> 4, m = lane & 15;
    int head = blockIdx.y;
    int i0 = blockIdx.x * R;
    int jstart = blockIdx.z * JLEN;

    __shared__ unsigned int ldsbm[R * ST];
    __shared__ unsigned short ldsbt[2][BUFO];
    __shared__ float ldsf2[JLEN];
    __shared__ float ldse2p[JLEN];
    __shared__ float ldse2n[JLEN];

    const unsigned short* BTh = BTh_all + (size_t)head * CR * 4096;
    const float* f1 = f1_all + head * 4096;
    const float* f2 = f2_all + head * 4096;

    // stage bitmask slice
    for (int c = tid; c < NU4; c += 256) {
        int row = c / PR, part = c % PR;
        uint4 v = *(const uint4*)(bmb + (size_t)(i0 + row) * 512 + (jstart >> 3) + part * 16);
        *(uint4*)&ldsbm[row * ST + part * 4] = v;
    }
    // stage f2 slice + factored-exp tables (f2 already log2e-scaled)
    for (int c = tid; c < JLEN / 4; c += 256) {
        float4 v = *(const float4*)(f2 + jstart + c * 4);
        *(float4*)&ldsf2[c * 4] = v;
        float4 ep, en;
        ep.x = __builtin_amdgcn_exp2f(v.x); en.x = __builtin_amdgcn_exp2f(0.01f * v.x);
        ep.y = __builtin_amdgcn_exp2f(v.y); en.y = __builtin_amdgcn_exp2f(0.01f * v.y);
        ep.z = __builtin_amdgcn_exp2f(v.z); en.z = __builtin_amdgcn_exp2f(0.01f * v.z);
        ep.w = __builtin_amdgcn_exp2f(v.w); en.w = __builtin_amdgcn_exp2f(0.01f * v.w);
        *(float4*)&ldse2p[c * 4] = ep;
        *(float4*)&ldse2n[c * 4] = en;
    }

    // BT staging: thread t stages row t>>2, cols (t&3)*8 + {0,32} of each tile
    int sc = tid >> 2, sp = tid & 3;
    bool stager = (NCT == 4) ? true : (tid < CR * 4);
    const unsigned short* sbase = BTh + (size_t)sc * 4096 + jstart + sp * 8;
    unsigned short* swr0 = &ldsbt[0][0] + sc * TSTR + sp * 8;

    uint4 vA0, vA1, vB0, vB1;
    if (stager) {
        uint4 t00 = *(const uint4*)(sbase);
        uint4 t01 = *(const uint4*)(sbase + 32);
        *(uint4*)(swr0) = t00;                      // tile 0 -> buf 0
        *(uint4*)(swr0 + 32) = t01;
        vB0 = *(const uint4*)(sbase + 64);          // tile 1 held in vB
        vB1 = *(const uint4*)(sbase + 96);
    }

    int col0 = head * CR;
    int r0 = wave * 16;
    float f1s0 = f1[i0 + r0 + m];
    float e1p0 = __builtin_amdgcn_exp2f(f1s0);
    float e1n0 = __builtin_amdgcn_exp2f(0.01f * f1s0);

    f32x4 acc0[NCT] = {};
    f32x4 accz = {};                                // z via MFMA (P @ ones)
    bf16x8 ones;
    {
        union { bf16x8 v; __bf16 e[8]; } o;
        #pragma unroll
        for (int j = 0; j < 8; j++) o.e[j] = (__bf16)1.0f;
        ones = o.v;
    }
    int mrow = (r0 + m) * ST;

    auto compute = [&](int it, int cur) {
        int jl = it * 64;
        unsigned long long mw = *(const unsigned long long*)&ldsbm[mrow + 2 * it];
        const unsigned short* rb = &ldsbt[0][0] + cur * BUFO;
        #pragma unroll
        for (int js = 0; js < 2; js++) {
            unsigned int md0 = (js == 0) ? (unsigned int)mw : (unsigned int)(mw >> 32);
            int jb = jl + js * 32 + q * 8;
            const float4* f2p = (const float4*)&ldsf2[jb];
            float4 fa = f2p[0], fb = f2p[1];
            const float4* epp = (const float4*)&ldse2p[jb];
            float4 pa = epp[0], pb = epp[1];
            const float4* enp = (const float4*)&ldse2n[jb];
            float4 na = enp[0], nb = enp[1];
            float fv[8] = {fa.x, fa.y, fa.z, fa.w, fb.x, fb.y, fb.z, fb.w};
            float ev[8] = {pa.x, pa.y, pa.z, pa.w, pb.x, pb.y, pb.z, pb.w};
            float nv[8] = {na.x, na.y, na.z, na.w, nb.x, nb.y, nb.z, nb.w};
            float pv0[8];
            #pragma unroll
            for (int jj = 0; jj < 8; jj++) {
                int bit = q * 8 + jj;
                float s0 = f1s0 + fv[jj];
                bool pos = s0 > 0.0f;
                float p0 = (pos ? e1p0 : e1n0) * (pos ? ev[jj] : nv[jj]);
                bool v0 = ((md0 >> bit) & 1u) && (s0 != 0.0f);
                pv0[jj] = v0 ? p0 : 0.0f;
            }
            bf16x8 ah0 = cvt8(pv0);
            #pragma unroll
            for (int ct = 0; ct < NCT; ct++) {
                bf16x8 bh = *(const bf16x8*)(rb + (ct * 16 + m) * TSTR + js * 32 + q * 8);
                acc0[ct] = __builtin_amdgcn_mfma_f32_16x16x32_bf16(ah0, bh, acc0[ct], 0, 0, 0);
            }
            accz = __builtin_amdgcn_mfma_f32_16x16x32_bf16(ah0, ones, accz, 0, 0, 0);
        }
    };

    LGKM0;                                           // publish prologue ds_writes
    for (int itp = 0; itp + 2 < NIT; itp += 2) {
        __builtin_amdgcn_s_barrier();
        if (stager) {                                // prefetch tile itp+2 -> vA
            vA0 = *(const uint4*)(sbase + (itp + 2) * 64);
            vA1 = *(const uint4*)(sbase + (itp + 2) * 64 + 32);
        }
        compute(itp, 0);
        if (stager) {                                // write tile itp+1 -> buf1
            *(uint4*)(swr0 + BUFO) = vB0;
            *(uint4*)(swr0 + BUFO + 32) = vB1;
        }
        LGKM0;
        __builtin_amdgcn_s_barrier();
        if (stager) {                                // prefetch tile itp+3 -> vB
            vB0 = *(const uint4*)(sbase + (itp + 3) * 64);
            vB1 = *(const uint4*)(sbase + (itp + 3) * 64 + 32);
        }
        compute(itp + 1, 1);
        if (stager) {                                // write tile itp+2 -> buf0
            *(uint4*)(swr0) = vA0;
            *(uint4*)(swr0 + 32) = vA1;
        }
        LGKM0;
    }
    __builtin_amdgcn_s_barrier();
    compute(NIT - 2, 0);
    if (stager) {                                    // write tile NIT-1 -> buf1
        *(uint4*)(swr0 + BUFO) = vB0;
        *(uint4*)(swr0 + BUFO + 32) = vB1;
    }
    LGKM0;
    __builtin_amdgcn_s_barrier();
    compute(NIT - 1, 1);

    // z epilogue: accz reg r holds z[i0+r0+q*4+r] (replicated over m)
    if (m == 0) {
        #pragma unroll
        for (int r = 0; r < 4; r++) {
            int zi = head * 4096 + i0 + r0 + q * 4 + r;
            atomicAdd(&zacc[zi], accz[r]);
        }
    }
    #pragma unroll
    for (int ct = 0; ct < NCT; ct++)
        #pragma unroll
        for (int r = 0; r < 4; r++) {
            int col = col0 + ct * 16 + m;
            int rowA = i0 + r0 + q * 4 + r;
            atomicAdd(&pacc[rowA * pstride + col], acc0[ct][r]);
        }
}

// ---------------- Fin1c: helu = elu(p1 / z1), coalesced, hi/lo bf16 -----------
__global__ __launch_bounds__(256)
void fin1c(const float* __restrict__ pp, const float* __restrict__ zp,
           unsigned short* __restrict__ hh, unsigned short* __restrict__ hl) {
    int row = blockIdx.x, col = threadIdx.x;
    float s = pp[(size_t)row * 256 + col];
    int head = col >> 6;
    float zz = zp[head * 4096 + row];
    float v = s / zz;
    v = (v > 0.f) ? v : (__expf(v) - 1.0f);
    splitstore(&hh[row * 256 + col], &hl[row * 256 + col], v);
}

// ---------------- K3: h2 = h_elu @ W2^T (in-register W2 split), fq ------------
__global__ __launch_bounds__(256)
void k3_layer2(const unsigned short* __restrict__ helu_hi,
               const unsigned short* __restrict__ helu_lo,
               const float* __restrict__ w2,
               const float* __restrict__ a12,
               const float* __restrict__ a22,
               unsigned short* __restrict__ h2t_hi,
               float* __restrict__ fq) {
    int tid = threadIdx.x, wave = tid >> 6, lane = tid & 63;
    int q = lane >> 4, m = lane & 15;
    int i0 = (blockIdx.x * 4 + wave) * 16;
    f32x4 acc = {};
    #pragma unroll
    for (int k0 = 0; k0 < 256; k0 += 32) {
        bf16x8 ah = *(const bf16x8*)(helu_hi + (i0 + m) * 256 + k0 + q * 8);
        bf16x8 al = *(const bf16x8*)(helu_lo + (i0 + m) * 256 + k0 + q * 8);
        bf16x8 bh, bl;
        split8(w2 + m * 256 + k0 + q * 8, bh, bl);
        acc = __builtin_amdgcn_mfma_f32_16x16x32_bf16(ah, bh, acc, 0, 0, 0);
        acc = __builtin_amdgcn_mfma_f32_16x16x32_bf16(al, bh, acc, 0, 0, 0);
        acc = __builtin_amdgcn_mfma_f32_16x16x32_bf16(ah, bl, acc, 0, 0, 0);
    }
    float a1v = a12[m], a2v = a22[m];
    #pragma unroll
    for (int r = 0; r < 4; r++) {
        float v = acc[r];
        int i = i0 + q * 4 + r;
        h2t_hi[m * 4096 + i] = f2bfh(v);
        float s1 = v * a1v, s2 = v * a2v;
        #pragma unroll
        for (int off = 1; off < 16; off <<= 1) {
            s1 += __shfl_xor(s1, off);
            s2 += __shfl_xor(s2, off);
        }
        if (m == 0) { fq[i] = s1 * LOG2E; fq[4096 + i] = s2 * LOG2E; }
    }
}

// ---------------- Fin2: out = p2/z2 (f32, single atomic-accumulated buffers) --
__global__ __launch_bounds__(128)
void fin2(const float* __restrict__ pp, const float* __restrict__ zp,
          float* __restrict__ out) {
    int idx = blockIdx.x * 128 + threadIdx.x;      // 65536
    out[idx] = pp[idx] / zp[idx >> 4];
}

extern "C" void kernel_launch(void* const* d_in, const int* in_sizes, int n_in,
                              void* d_out, int out_size, void* d_ws, size_t ws_size,
                              hipStream_t stream) {
    const float* x   = (const float*)d_in[0];
    const int*   adj = (const int*)d_in[1];
    const float* w1  = (const float*)d_in[2];
    const float* a11 = (const float*)d_in[3];
    const float* a21 = (const float*)d_in[4];
    const float* w2  = (const float*)d_in[5];
    const float* a12 = (const float*)d_in[6];
    const float* a22 = (const float*)d_in[7];
    float* out = (float*)d_out;

    uint8_t* w = (uint8_t*)d_ws;
    unsigned long long* bm  = (unsigned long long*)(w);                       // 2 MB
    unsigned short* h1t_hi  = (unsigned short*)(w + (2u << 20));              // 2 MB
    unsigned short* h2t_hi  = (unsigned short*)(w + (4u << 20));              // 128 KB
    float*          fvals   = (float*)(w + (4u << 20) + (128u << 10));        // 128 KB
    float*          fq      = (float*)(w + (4u << 20) + (256u << 10));        // 32 KB
    unsigned short* helu_hi = (unsigned short*)(w + (4u << 20) + (560u << 10)); // 2 MB
    unsigned short* helu_lo = (unsigned short*)(w + (4u << 20) + (2608u << 10)); // 2 MB

    // atomic accumulators (contiguous, zeroed by kpre2's zero role):
    // p1 4MB | z1 64KB | p2 256KB | z2 16KB  = 4.33 MB
    float* p1 = (float*)(w + (9u << 20));
    float* z1 = p1 + (size_t)4096 * 256;
    float* p2 = z1 + 4 * 4096;
    float* z2 = p2 + 4096 * 16;

    kpre2<<<9556, 256, 0, stream>>>(adj, bm, x, w1, a11, a21, h1t_hi, fvals,
                                    (float4*)p1);
    attn_kernel<4, 1024><<<dim3(64, 4, 4), 256, 0, stream>>>(
        (const unsigned char*)bm, fvals, fvals + 16384, h1t_hi, p1, z1, 256);
    fin1c<<<4096, 256, 0, stream>>>(p1, z1, helu_hi, helu_lo);
    k3_layer2<<<64, 256, 0, stream>>>(helu_hi, helu_lo, w2, a12, a22,
                                      h2t_hi, fq);
    attn_kernel<1, 256><<<dim3(64, 1, 16), 256, 0, stream>>>(
        (const unsigned char*)bm, fq, fq + 4096, h2t_hi, p2, z2, 16);
    fin2<<<512, 128, 0, stream>>>(p2, z2, out);
}